// Round 5
// baseline (637.474 us; speedup 1.0000x reference)
//
#include <hip/hip_runtime.h>

#define S_LEN 2048
#define HID 2048
#define NH 16
#define NKV 2
#define HD 256
#define MAXSEQ 4096
#define NALL 9216   // 8192 qg | 512 k | 512 v
#define RD 64

typedef __attribute__((ext_vector_type(8))) short short8_t;   // 8 bf16 (4 VGPRs)
typedef __attribute__((ext_vector_type(4))) float float4_t;   // MFMA C/D

// DPP cross-lane over a 16-lane row (VALU pipe, not LDS): xor1, xor2, half-mirror, mirror
#define DPPF(x, ctrl) __builtin_bit_cast(float, __builtin_amdgcn_update_dpp( \
    __builtin_bit_cast(int, x), __builtin_bit_cast(int, x), ctrl, 0xF, 0xF, false))

__device__ __forceinline__ unsigned short f2b(float f) {
  union { float f; unsigned u; } v; v.f = f;
  unsigned u = v.u;
  return (unsigned short)((u + 0x7FFFu + ((u >> 16) & 1u)) >> 16);  // RNE, finite data
}

__device__ __forceinline__ void gload_lds16(const void* g, void* l) {
  __builtin_amdgcn_global_load_lds(
      (const __attribute__((address_space(1))) void*)g,
      (__attribute__((address_space(3))) void*)l, 16, 0, 0);
}

// ---------------- fused fp32->bf16 converts + cache-pad zeroing (one dispatch) ----------------
// segments (float4 units): hidden 1048576 | qw 4194304 | kw 262144 | vw 262144 | ow 2097152
// then 4 zero regions of 131072 float4 each (k/v cache pad rows [S, MAX_SEQ)).
__global__ void fused_cvt(const float* __restrict__ hidden, const float* __restrict__ qw,
                          const float* __restrict__ kw, const float* __restrict__ vw,
                          const float* __restrict__ ow,
                          unsigned short* __restrict__ hidb, unsigned short* __restrict__ wallb,
                          unsigned short* __restrict__ wob,
                          float* __restrict__ kcache, float* __restrict__ vcache) {
  const long i = (long)blockIdx.x * 256 + threadIdx.x;
  const long N0 = 1048576, N1 = N0 + 4194304, N2 = N1 + 262144, N3 = N2 + 262144,
             N4 = N3 + 2097152;
  if (i < N4) {
    const float* s; unsigned short* d; long j;
    if (i < N0)      { s = hidden; d = hidb;  j = i; }
    else if (i < N1) { s = qw; d = wallb;                        j = i - N0; }
    else if (i < N2) { s = kw; d = wallb + (size_t)8192*HID;     j = i - N1; }
    else if (i < N3) { s = vw; d = wallb + (size_t)8704*HID;     j = i - N2; }
    else             { s = ow; d = wob;                          j = i - N3; }
    float4 v = ((const float4*)s)[j];
    short4 o;
    o.x = (short)f2b(v.x); o.y = (short)f2b(v.y);
    o.z = (short)f2b(v.z); o.w = (short)f2b(v.w);
    ((short4*)d)[j] = o;
  } else {
    long j = i - N4;                 // 0 .. 524287
    int region = (int)(j >> 17);     // 131072 float4 per pad region
    long o = j & 131071;
    float* base = (region < 2 ? kcache : vcache)
                + (size_t)(region & 1) * MAXSEQ * HD + (size_t)S_LEN * HD;
    float4 z; z.x = 0.f; z.y = 0.f; z.z = 0.f; z.w = 0.f;
    ((float4*)base)[o] = z;
  }
}

// ---------------- bf16 GEMM, C = A * B^T  (A: MxK, B: NxK row-major, C: MxN f32) ----------------
// m97 structure + BK=64 + XOR-swizzled LDS (chunk' = chunk ^ (row&7)).
template<int BM, int BN, int MI, int NI>
__global__ __launch_bounds__(256, 2) void gemm_bt(
    const unsigned short* __restrict__ A, const unsigned short* __restrict__ B,
    float* __restrict__ C, int M, int N, int K) {
  constexpr int BK = 64;
  __shared__ unsigned short As[BM * BK];
  __shared__ unsigned short Bs[BN * BK];
  const int tid = threadIdx.x;
  const int lane = tid & 63;
  const int w = tid >> 6;
  const int wr = w >> 1, wc = w & 1;
  const int l15 = lane & 15, l4 = lane >> 4;
  const int M0 = blockIdx.y * BM, N0 = blockIdx.x * BN;
  float4_t acc[MI][NI] = {};
  for (int kt = 0; kt < K; kt += BK) {
    __syncthreads();
#pragma unroll
    for (int i = 0; i < BM/32; ++i) {
      int c = tid + i*256;
      int row = c >> 3;
      gload_lds16(A + (size_t)(M0 + row)*K + kt + ((c & 7) ^ (row & 7))*8, (char*)As + c*16);
    }
#pragma unroll
    for (int i = 0; i < BN/32; ++i) {
      int c = tid + i*256;
      int row = c >> 3;
      gload_lds16(B + (size_t)(N0 + row)*K + kt + ((c & 7) ^ (row & 7))*8, (char*)Bs + c*16);
    }
    __syncthreads();
#pragma unroll
    for (int ks = 0; ks < 2; ++ks) {
      short8_t af[MI], bf[NI];
#pragma unroll
      for (int mi = 0; mi < MI; ++mi) {
        int row = wr*(BM/2) + mi*16 + l15;
        af[mi] = *(const short8_t*)&As[row*BK + ((ks*4 + l4) ^ (l15 & 7))*8];
      }
#pragma unroll
      for (int ni = 0; ni < NI; ++ni) {
        int row = wc*(BN/2) + ni*16 + l15;
        bf[ni] = *(const short8_t*)&Bs[row*BK + ((ks*4 + l4) ^ (l15 & 7))*8];
      }
#pragma unroll
      for (int mi = 0; mi < MI; ++mi)
#pragma unroll
        for (int ni = 0; ni < NI; ++ni)
          acc[mi][ni] = __builtin_amdgcn_mfma_f32_16x16x32_bf16(af[mi], bf[ni], acc[mi][ni], 0, 0, 0);
    }
  }
#pragma unroll
  for (int mi = 0; mi < MI; ++mi) {
    int rb = M0 + wr*(BM/2) + mi*16 + l4*4;
#pragma unroll
    for (int ni = 0; ni < NI; ++ni) {
      int col = N0 + wc*(BN/2) + ni*16 + l15;
#pragma unroll
      for (int r = 0; r < 4; ++r)
        C[(size_t)(rb + r)*N + col] = acc[mi][ni][r];
    }
  }
}

// ---------------- post: RMSNorm + RoPE + split + caches + V^T ----------------
__global__ void postproc(const float* __restrict__ C1,
                         const float* __restrict__ cosb, const float* __restrict__ sinb,
                         const float* __restrict__ qnw, const float* __restrict__ knw,
                         unsigned short* __restrict__ qb, unsigned short* __restrict__ kb,
                         unsigned short* __restrict__ vtb,
                         float* __restrict__ kcache, float* __restrict__ vcache) {
  const int w = threadIdx.x >> 6, lane = threadIdx.x & 63;
  const int s = blockIdx.x*4 + w;
  const int t = blockIdx.y;
  const int d = lane*4;
  const float* rowp;
  if (t < 16)      rowp = C1 + (size_t)s*NALL + t*512;
  else if (t < 18) rowp = C1 + (size_t)s*NALL + 8192 + (t-16)*256;
  else             rowp = C1 + (size_t)s*NALL + 8704 + (t-18)*256;
  float4 x = *(const float4*)(rowp + d);
  if (t >= 18) {
    int kvi = t - 18;
    *(float4*)(vcache + (size_t)kvi*MAXSEQ*HD + (size_t)s*HD + d) = x;
    unsigned short* vt = vtb + (size_t)kvi*HD*S_LEN;
    vt[(size_t)(d+0)*S_LEN + s] = f2b(x.x);
    vt[(size_t)(d+1)*S_LEN + s] = f2b(x.y);
    vt[(size_t)(d+2)*S_LEN + s] = f2b(x.z);
    vt[(size_t)(d+3)*S_LEN + s] = f2b(x.w);
    return;
  }
  float ss = x.x*x.x + x.y*x.y + x.z*x.z + x.w*x.w;
#pragma unroll
  for (int o = 32; o >= 1; o >>= 1) ss += __shfl_xor(ss, o, 64);
  float rn = rsqrtf(ss*(1.0f/256.0f) + 1e-6f);
  const float* nw = (t < 16) ? qnw : knw;
  float4 g = *(const float4*)(nw + d);
  float4 y;
  y.x = x.x*rn*(1.f+g.x); y.y = x.y*rn*(1.f+g.y);
  y.z = x.z*rn*(1.f+g.z); y.w = x.w*rn*(1.f+g.w);
  float px = __shfl_xor(y.x, 8, 64);
  float py = __shfl_xor(y.y, 8, 64);
  float pz = __shfl_xor(y.z, 8, 64);
  float pw = __shfl_xor(y.w, 8, 64);
  if (lane < 16) {
    float sgn = (lane & 8) ? 1.f : -1.f;
    float4 cs = *(const float4*)(cosb + (size_t)s*RD + d);
    float4 sn = *(const float4*)(sinb + (size_t)s*RD + d);
    y.x = y.x*cs.x + sgn*px*sn.x;
    y.y = y.y*cs.y + sgn*py*sn.y;
    y.z = y.z*cs.z + sgn*pz*sn.z;
    y.w = y.w*cs.w + sgn*pw*sn.w;
  }
  if (t < 16) {
    const float qs = 0.0625f * 1.44269504088896f;
    short4 o;
    o.x = (short)f2b(y.x*qs); o.y = (short)f2b(y.y*qs);
    o.z = (short)f2b(y.z*qs); o.w = (short)f2b(y.w*qs);
    *(short4*)(qb + (size_t)t*S_LEN*HD + (size_t)s*HD + d) = o;
  } else {
    int kvi = t - 16;
    *(float4*)(kcache + (size_t)kvi*MAXSEQ*HD + (size_t)s*HD + d) = y;
    short4 o;
    o.x = (short)f2b(y.x); o.y = (short)f2b(y.y);
    o.z = (short)f2b(y.z); o.w = (short)f2b(y.w);
    *(short4*)(kb + (size_t)kvi*S_LEN*HD + (size_t)s*HD + d) = o;
  }
}

// ---------------- flash attention + fused sigmoid gate ----------------
// 512 blocks x 128 threads (2 waves). Wave w owns 32 q-rows (2 groups of 16): every
// staged K/V byte now feeds 2 MFMAs per read — halves per-wave LDS traffic vs 16 rows.
// Balance: qt = (b&1) ? 31-g(t16) : g(t16), g(t)= t<8 ? t : 23-t — pair sums constant
// under BOTH consecutive and round-robin block placement.
// LDS: Ks 64x256 (32KB) | VTs 256x64 (32KB) | P 2 waves x 32x64 (8KB) = 72KB -> 2 blocks/CU.
__global__ __launch_bounds__(128, 1) void attn_kernel(
    const unsigned short* __restrict__ qb, const unsigned short* __restrict__ kb,
    const unsigned short* __restrict__ vtb, const float* __restrict__ C1,
    unsigned short* __restrict__ attnb) {
  __shared__ char smem[73728];
  unsigned short* Ks  = (unsigned short*)smem;
  unsigned short* VTs = (unsigned short*)(smem + 32768);
  const int tid = threadIdx.x, lane = tid & 63, w = tid >> 6;   // w in {0,1}
  const int l15 = lane & 15, l4 = lane >> 4;
  const int b = blockIdx.x;
  const int i2 = b >> 1;
  const int h = i2 & 15;
  const int t16 = i2 >> 4;                     // 0..15
  const int gt = (t16 < 8) ? t16 : 23 - t16;   // bijection with g(t)+g(t+8)=15
  const int qt = (b & 1) ? (31 - gt) : gt;
  const int kv = h >> 3;
  const int q0 = qt * 64;
  const unsigned short* Qb = qb + (size_t)h*S_LEN*HD;
  const unsigned short* Kb = kb + (size_t)kv*S_LEN*HD;
  const unsigned short* Vb = vtb + (size_t)kv*HD*S_LEN;
  unsigned short* Pw = (unsigned short*)(smem + 65536 + w*4096);   // private 32x64 bf16
  short8_t qf[2][8];
#pragma unroll
  for (int g = 0; g < 2; ++g)
#pragma unroll
    for (int kk = 0; kk < 8; ++kk)
      qf[g][kk] = *(const short8_t*)(Qb + (size_t)(q0 + w*32 + g*16 + l15)*HD + kk*32 + l4*8);
  float4_t oacc[2][16] = {};
  float m_run[2][4], l_run[2][4];
#pragma unroll
  for (int g = 0; g < 2; ++g)
#pragma unroll
    for (int r = 0; r < 4; ++r) { m_run[g][r] = -1e30f; l_run[g][r] = 0.f; }
  for (int kbI = 0; kbI <= qt; ++kbI) {
    const int k0 = kbI * 64;
    __syncthreads();                          // prev iter's LDS reads done
#pragma unroll
    for (int i = 0; i < 16; ++i) {            // K tile: 64 rows x 256, swizzled source col
      int c = tid + i*128;
      int row = c >> 5;
      gload_lds16(Kb + (size_t)(k0 + row)*HD + ((c & 31) ^ (row & 7))*8, (char*)Ks + c*16);
    }
#pragma unroll
    for (int i = 0; i < 16; ++i) {            // V^T tile: 256 rows x 64
      int c = tid + i*128;
      int row = c >> 3;
      gload_lds16(Vb + (size_t)row*S_LEN + k0 + ((c & 7) ^ (row & 7))*8, (char*)VTs + c*16);
    }
    __syncthreads();                          // staging drained
    float4_t sacc[2][4] = {};
#pragma unroll
    for (int nt = 0; nt < 4; ++nt)
#pragma unroll
      for (int kk = 0; kk < 8; ++kk) {
        short8_t bfr = *(const short8_t*)&Ks[(nt*16 + l15)*HD + ((kk*4 + l4) ^ (l15 & 7))*8];
        sacc[0][nt] = __builtin_amdgcn_mfma_f32_16x16x32_bf16(qf[0][kk], bfr, sacc[0][nt], 0, 0, 0);
        sacc[1][nt] = __builtin_amdgcn_mfma_f32_16x16x32_bf16(qf[1][kk], bfr, sacc[1][nt], 0, 0, 0);
      }
    if (kbI == qt) {                          // causal mask on diagonal tile
#pragma unroll
      for (int g = 0; g < 2; ++g)
#pragma unroll
        for (int nt = 0; nt < 4; ++nt)
#pragma unroll
          for (int r = 0; r < 4; ++r)
            if (nt*16 + l15 > w*32 + g*16 + l4*4 + r) sacc[g][nt][r] = -1e30f;
    }
#pragma unroll
    for (int g = 0; g < 2; ++g) {
      float alpha[4], p[4][4];
#pragma unroll
      for (int r = 0; r < 4; ++r) {
        float m0 = fmaxf(fmaxf(sacc[g][0][r], sacc[g][1][r]), fmaxf(sacc[g][2][r], sacc[g][3][r]));
        m0 = fmaxf(m0, DPPF(m0, 0xB1));       // quad_perm xor1
        m0 = fmaxf(m0, DPPF(m0, 0x4E));       // quad_perm xor2
        m0 = fmaxf(m0, DPPF(m0, 0x141));      // row_half_mirror
        m0 = fmaxf(m0, DPPF(m0, 0x140));      // row_mirror -> 16-lane max
        float mnew = fmaxf(m_run[g][r], m0);
        alpha[r] = exp2f(m_run[g][r] - mnew);
        m_run[g][r] = mnew;
        float sum = 0.f;
#pragma unroll
        for (int nt = 0; nt < 4; ++nt) {
          p[nt][r] = exp2f(sacc[g][nt][r] - mnew);
          sum += p[nt][r];
        }
        sum += DPPF(sum, 0xB1);
        sum += DPPF(sum, 0x4E);
        sum += DPPF(sum, 0x141);
        sum += DPPF(sum, 0x140);
        l_run[g][r] = l_run[g][r]*alpha[r] + sum;
      }
#pragma unroll
      for (int nt2 = 0; nt2 < 16; ++nt2) {
        oacc[g][nt2][0] *= alpha[0];
        oacc[g][nt2][1] *= alpha[1];
        oacc[g][nt2][2] *= alpha[2];
        oacc[g][nt2][3] *= alpha[3];
      }
      // P: D-layout -> A-layout via private LDS (same-wave RAW, lgkmcnt suffices)
#pragma unroll
      for (int nt = 0; nt < 4; ++nt)
#pragma unroll
        for (int r = 0; r < 4; ++r) {
          int prow = g*16 + l4*4 + r;
          int pcol = nt*16 + l15;
          Pw[prow*64 + (((pcol >> 3) ^ (prow & 7)))*8 + (pcol & 7)] = f2b(p[nt][r]);
        }
    }
    short8_t pf[2][2];
#pragma unroll
    for (int g = 0; g < 2; ++g) {
      pf[g][0] = *(const short8_t*)&Pw[(g*16 + l15)*64 + ((l4 ^ (l15 & 7)))*8];
      pf[g][1] = *(const short8_t*)&Pw[(g*16 + l15)*64 + (((l4 ^ 4) ^ (l15 & 7)))*8];
    }
#pragma unroll
    for (int nt2 = 0; nt2 < 16; ++nt2) {
      int vrow = nt2*16 + l15;
      short8_t v0 = *(const short8_t*)&VTs[vrow*64 + ((l4 ^ (l15 & 7)))*8];
      short8_t v1 = *(const short8_t*)&VTs[vrow*64 + (((l4 ^ 4) ^ (l15 & 7)))*8];
      oacc[0][nt2] = __builtin_amdgcn_mfma_f32_16x16x32_bf16(pf[0][0], v0, oacc[0][nt2], 0, 0, 0);
      oacc[0][nt2] = __builtin_amdgcn_mfma_f32_16x16x32_bf16(pf[0][1], v1, oacc[0][nt2], 0, 0, 0);
      oacc[1][nt2] = __builtin_amdgcn_mfma_f32_16x16x32_bf16(pf[1][0], v0, oacc[1][nt2], 0, 0, 0);
      oacc[1][nt2] = __builtin_amdgcn_mfma_f32_16x16x32_bf16(pf[1][1], v1, oacc[1][nt2], 0, 0, 0);
    }
  }
#pragma unroll
  for (int g = 0; g < 2; ++g) {
    float inv_l[4];
#pragma unroll
    for (int r = 0; r < 4; ++r) inv_l[r] = 1.f / l_run[g][r];
    const int srow0 = q0 + w*32 + g*16 + l4*4;
#pragma unroll
    for (int nt2 = 0; nt2 < 16; ++nt2) {
      int dim = nt2*16 + l15;
#pragma unroll
      for (int r = 0; r < 4; ++r) {
        int srow = srow0 + r;
        float gv = C1[(size_t)srow*NALL + h*512 + 256 + dim];
        float sg = 1.f / (1.f + __expf(-gv));
        attnb[(size_t)srow*(NH*HD) + h*HD + dim] = f2b(oacc[g][nt2][r] * inv_l[r] * sg);
      }
    }
  }
}

extern "C" void kernel_launch(void* const* d_in, const int* in_sizes, int n_in,
                              void* d_out, int out_size, void* d_ws, size_t ws_size,
                              hipStream_t stream) {
  const float* hidden = (const float*)d_in[0];
  const float* cosb   = (const float*)d_in[1];
  const float* sinb   = (const float*)d_in[2];
  const float* qw     = (const float*)d_in[3];
  const float* kw     = (const float*)d_in[4];
  const float* vw     = (const float*)d_in[5];
  const float* ow     = (const float*)d_in[6];
  const float* qnw    = (const float*)d_in[7];
  const float* knw    = (const float*)d_in[8];
  float* out    = (float*)d_out;
  float* kcache = out + (size_t)S_LEN*HID;
  float* vcache = kcache + (size_t)NKV*MAXSEQ*HD;

  char* ws = (char*)d_ws;
  size_t off = 0;
  auto alloc = [&](size_t bytes) -> char* {
    char* p = ws + off; off += (bytes + 255) & ~(size_t)255; return p;
  };
  unsigned short* hidb  = (unsigned short*)alloc((size_t)S_LEN*HID*2);     //  8 MB
  unsigned short* wallb = (unsigned short*)alloc((size_t)NALL*HID*2);      // 36 MB
  unsigned short* wob   = (unsigned short*)alloc((size_t)HID*NH*HD*2);     // 16 MB
  float*          C1    = (float*)alloc((size_t)S_LEN*NALL*4);             // 72 MB
  unsigned short* qb    = (unsigned short*)alloc((size_t)NH*S_LEN*HD*2);   // 16 MB
  unsigned short* kb    = (unsigned short*)alloc((size_t)NKV*S_LEN*HD*2);  //  2 MB
  unsigned short* vtb   = (unsigned short*)alloc((size_t)NKV*HD*S_LEN*2);  //  2 MB
  unsigned short* attnb = (unsigned short*)alloc((size_t)S_LEN*NH*HD*2);   // 16 MB

  // all fp32->bf16 converts + cache-pad zeroing in one dispatch (8388608 float4 units)
  fused_cvt<<<32768, 256, 0, stream>>>(hidden, qw, kw, vw, ow,
                                       hidb, wallb, wob, kcache, vcache);

  // fused QKV projection: C1 = hidden @ [Wq|Wk|Wv]^T  (2048 x 9216)
  gemm_bt<128,128,4,4><<<dim3(NALL/128, S_LEN/128), 256, 0, stream>>>(
      hidb, wallb, C1, S_LEN, NALL, HID);

  // RMSNorm + RoPE + caches + V^T + q pre-scale
  postproc<<<dim3(S_LEN/4, 20), 256, 0, stream>>>(
      C1, cosb, sinb, qnw, knw, qb, kb, vtb, kcache, vcache);

  // flash attention + sigmoid gate -> attnb (S x H*HD bf16)
  attn_kernel<<<512, 128, 0, stream>>>(qb, kb, vtb, C1, attnb);

  // hidden_out = attnb @ Wo^T  (2048 x 2048, K=4096)
  gemm_bt<128,128,4,4><<<dim3(HID/128, S_LEN/128), 256, 0, stream>>>(
      attnb, wob, out, S_LEN, HID, NH*HD);
}

// Round 6
// 471.065 us; speedup vs baseline: 1.3533x; 1.3533x over previous
//
#include <hip/hip_runtime.h>

#define S_LEN 2048
#define HID 2048
#define NH 16
#define NKV 2
#define HD 256
#define MAXSEQ 4096
#define NALL 9216   // 8192 qg | 512 k | 512 v
#define RD 64

typedef __attribute__((ext_vector_type(8))) short short8_t;   // 8 bf16 (4 VGPRs)
typedef __attribute__((ext_vector_type(4))) float float4_t;   // MFMA C/D

// DPP cross-lane over a 16-lane row (VALU pipe, not LDS): xor1, xor2, half-mirror, mirror
#define DPPF(x, ctrl) __builtin_bit_cast(float, __builtin_amdgcn_update_dpp( \
    __builtin_bit_cast(int, x), __builtin_bit_cast(int, x), ctrl, 0xF, 0xF, false))

__device__ __forceinline__ unsigned short f2b(float f) {
  union { float f; unsigned u; } v; v.f = f;
  unsigned u = v.u;
  return (unsigned short)((u + 0x7FFFu + ((u >> 16) & 1u)) >> 16);  // RNE, finite data
}

__device__ __forceinline__ void gload_lds16(const void* g, void* l) {
  __builtin_amdgcn_global_load_lds(
      (const __attribute__((address_space(1))) void*)g,
      (__attribute__((address_space(3))) void*)l, 16, 0, 0);
}

// ---------------- fused fp32->bf16 converts + cache-pad zeroing (one dispatch) ----------------
__global__ void fused_cvt(const float* __restrict__ hidden, const float* __restrict__ qw,
                          const float* __restrict__ kw, const float* __restrict__ vw,
                          const float* __restrict__ ow,
                          unsigned short* __restrict__ hidb, unsigned short* __restrict__ wallb,
                          unsigned short* __restrict__ wob,
                          float* __restrict__ kcache, float* __restrict__ vcache) {
  const long i = (long)blockIdx.x * 256 + threadIdx.x;
  const long N0 = 1048576, N1 = N0 + 4194304, N2 = N1 + 262144, N3 = N2 + 262144,
             N4 = N3 + 2097152;
  if (i < N4) {
    const float* s; unsigned short* d; long j;
    if (i < N0)      { s = hidden; d = hidb;  j = i; }
    else if (i < N1) { s = qw; d = wallb;                        j = i - N0; }
    else if (i < N2) { s = kw; d = wallb + (size_t)8192*HID;     j = i - N1; }
    else if (i < N3) { s = vw; d = wallb + (size_t)8704*HID;     j = i - N2; }
    else             { s = ow; d = wob;                          j = i - N3; }
    float4 v = ((const float4*)s)[j];
    short4 o;
    o.x = (short)f2b(v.x); o.y = (short)f2b(v.y);
    o.z = (short)f2b(v.z); o.w = (short)f2b(v.w);
    ((short4*)d)[j] = o;
  } else {
    long j = i - N4;                 // 0 .. 524287
    int region = (int)(j >> 17);     // 131072 float4 per pad region
    long o = j & 131071;
    float* base = (region < 2 ? kcache : vcache)
                + (size_t)(region & 1) * MAXSEQ * HD + (size_t)S_LEN * HD;
    float4 z; z.x = 0.f; z.y = 0.f; z.z = 0.f; z.w = 0.f;
    ((float4*)base)[o] = z;
  }
}

// ---------------- bf16 GEMM, C = A * B^T  (A: MxK, B: NxK row-major, C: MxN f32) ----------------
// m97 structure + BK=64 + XOR-swizzled LDS (chunk' = chunk ^ (row&7)).
template<int BM, int BN, int MI, int NI>
__global__ __launch_bounds__(256, 2) void gemm_bt(
    const unsigned short* __restrict__ A, const unsigned short* __restrict__ B,
    float* __restrict__ C, int M, int N, int K) {
  constexpr int BK = 64;
  __shared__ unsigned short As[BM * BK];
  __shared__ unsigned short Bs[BN * BK];
  const int tid = threadIdx.x;
  const int lane = tid & 63;
  const int w = tid >> 6;
  const int wr = w >> 1, wc = w & 1;
  const int l15 = lane & 15, l4 = lane >> 4;
  const int M0 = blockIdx.y * BM, N0 = blockIdx.x * BN;
  float4_t acc[MI][NI] = {};
  for (int kt = 0; kt < K; kt += BK) {
    __syncthreads();
#pragma unroll
    for (int i = 0; i < BM/32; ++i) {
      int c = tid + i*256;
      int row = c >> 3;
      gload_lds16(A + (size_t)(M0 + row)*K + kt + ((c & 7) ^ (row & 7))*8, (char*)As + c*16);
    }
#pragma unroll
    for (int i = 0; i < BN/32; ++i) {
      int c = tid + i*256;
      int row = c >> 3;
      gload_lds16(B + (size_t)(N0 + row)*K + kt + ((c & 7) ^ (row & 7))*8, (char*)Bs + c*16);
    }
    __syncthreads();
#pragma unroll
    for (int ks = 0; ks < 2; ++ks) {
      short8_t af[MI], bf[NI];
#pragma unroll
      for (int mi = 0; mi < MI; ++mi) {
        int row = wr*(BM/2) + mi*16 + l15;
        af[mi] = *(const short8_t*)&As[row*BK + ((ks*4 + l4) ^ (l15 & 7))*8];
      }
#pragma unroll
      for (int ni = 0; ni < NI; ++ni) {
        int row = wc*(BN/2) + ni*16 + l15;
        bf[ni] = *(const short8_t*)&Bs[row*BK + ((ks*4 + l4) ^ (l15 & 7))*8];
      }
#pragma unroll
      for (int mi = 0; mi < MI; ++mi)
#pragma unroll
        for (int ni = 0; ni < NI; ++ni)
          acc[mi][ni] = __builtin_amdgcn_mfma_f32_16x16x32_bf16(af[mi], bf[ni], acc[mi][ni], 0, 0, 0);
    }
  }
#pragma unroll
  for (int mi = 0; mi < MI; ++mi) {
    int rb = M0 + wr*(BM/2) + mi*16 + l4*4;
#pragma unroll
    for (int ni = 0; ni < NI; ++ni) {
      int col = N0 + wc*(BN/2) + ni*16 + l15;
#pragma unroll
      for (int r = 0; r < 4; ++r)
        C[(size_t)(rb + r)*N + col] = acc[mi][ni][r];
    }
  }
}

// ---------------- post: RMSNorm + RoPE + split + caches + V^T ----------------
__global__ void postproc(const float* __restrict__ C1,
                         const float* __restrict__ cosb, const float* __restrict__ sinb,
                         const float* __restrict__ qnw, const float* __restrict__ knw,
                         unsigned short* __restrict__ qb, unsigned short* __restrict__ kb,
                         unsigned short* __restrict__ vtb,
                         float* __restrict__ kcache, float* __restrict__ vcache) {
  const int w = threadIdx.x >> 6, lane = threadIdx.x & 63;
  const int s = blockIdx.x*4 + w;
  const int t = blockIdx.y;
  const int d = lane*4;
  const float* rowp;
  if (t < 16)      rowp = C1 + (size_t)s*NALL + t*512;
  else if (t < 18) rowp = C1 + (size_t)s*NALL + 8192 + (t-16)*256;
  else             rowp = C1 + (size_t)s*NALL + 8704 + (t-18)*256;
  float4 x = *(const float4*)(rowp + d);
  if (t >= 18) {
    int kvi = t - 18;
    *(float4*)(vcache + (size_t)kvi*MAXSEQ*HD + (size_t)s*HD + d) = x;
    unsigned short* vt = vtb + (size_t)kvi*HD*S_LEN;
    vt[(size_t)(d+0)*S_LEN + s] = f2b(x.x);
    vt[(size_t)(d+1)*S_LEN + s] = f2b(x.y);
    vt[(size_t)(d+2)*S_LEN + s] = f2b(x.z);
    vt[(size_t)(d+3)*S_LEN + s] = f2b(x.w);
    return;
  }
  float ss = x.x*x.x + x.y*x.y + x.z*x.z + x.w*x.w;
#pragma unroll
  for (int o = 32; o >= 1; o >>= 1) ss += __shfl_xor(ss, o, 64);
  float rn = rsqrtf(ss*(1.0f/256.0f) + 1e-6f);
  const float* nw = (t < 16) ? qnw : knw;
  float4 g = *(const float4*)(nw + d);
  float4 y;
  y.x = x.x*rn*(1.f+g.x); y.y = x.y*rn*(1.f+g.y);
  y.z = x.z*rn*(1.f+g.z); y.w = x.w*rn*(1.f+g.w);
  float px = __shfl_xor(y.x, 8, 64);
  float py = __shfl_xor(y.y, 8, 64);
  float pz = __shfl_xor(y.z, 8, 64);
  float pw = __shfl_xor(y.w, 8, 64);
  if (lane < 16) {
    float sgn = (lane & 8) ? 1.f : -1.f;
    float4 cs = *(const float4*)(cosb + (size_t)s*RD + d);
    float4 sn = *(const float4*)(sinb + (size_t)s*RD + d);
    y.x = y.x*cs.x + sgn*px*sn.x;
    y.y = y.y*cs.y + sgn*py*sn.y;
    y.z = y.z*cs.z + sgn*pz*sn.z;
    y.w = y.w*cs.w + sgn*pw*sn.w;
  }
  if (t < 16) {
    const float qs = 0.0625f * 1.44269504088896f;
    short4 o;
    o.x = (short)f2b(y.x*qs); o.y = (short)f2b(y.y*qs);
    o.z = (short)f2b(y.z*qs); o.w = (short)f2b(y.w*qs);
    *(short4*)(qb + (size_t)t*S_LEN*HD + (size_t)s*HD + d) = o;
  } else {
    int kvi = t - 16;
    *(float4*)(kcache + (size_t)kvi*MAXSEQ*HD + (size_t)s*HD + d) = y;
    short4 o;
    o.x = (short)f2b(y.x); o.y = (short)f2b(y.y);
    o.z = (short)f2b(y.z); o.w = (short)f2b(y.w);
    *(short4*)(kb + (size_t)kvi*S_LEN*HD + (size_t)s*HD + d) = o;
  }
}

// ---------------- flash attention + fused sigmoid gate ----------------
// R4 shape (512 blocks x 256 thr, 4 waves x 16 q-rows) with Nk=32 K-tiles:
// half-size staging per barrier -> finer pipeline interleave between the 2
// co-resident blocks, same total LDS traffic/MFMA. LDS 36KB:
//   Ks 32x256 (16KB) | VTs 256x32 (16KB) | P 4 waves x 16x32 (4KB, private)
// Swizzles: K chunk' = chunk ^ (row&7) (32 chunks/row); VT/P (4 chunks/row):
// chunk' = chunk ^ ((row>>1)&3) -> reads 2-way = free.
__global__ __launch_bounds__(256, 2) void attn_kernel(
    const unsigned short* __restrict__ qb, const unsigned short* __restrict__ kb,
    const unsigned short* __restrict__ vtb, const float* __restrict__ C1,
    unsigned short* __restrict__ attnb) {
  __shared__ char smem[36864];
  unsigned short* Ks  = (unsigned short*)smem;            // 32 x 256
  unsigned short* VTs = (unsigned short*)(smem + 16384);  // 256 x 32
  const int tid = threadIdx.x, lane = tid & 63, w = tid >> 6;
  const int l15 = lane & 15, l4 = lane >> 4;
  const int b = blockIdx.x;
  const int i2 = b >> 1;
  const int h = i2 & 15;
  const int t16 = i2 >> 4;                    // 0..15
  const int qt = (b & 1) ? (31 - t16) : t16;  // adjacent blocks: qt sums to 31
  const int kv = h >> 3;                      // GROUPS = 8
  const int q0 = qt * 64;
  const unsigned short* Qb = qb + (size_t)h*S_LEN*HD;
  const unsigned short* Kb = kb + (size_t)kv*S_LEN*HD;
  const unsigned short* Vb = vtb + (size_t)kv*HD*S_LEN;
  unsigned short* Pw = (unsigned short*)(smem + 32768 + w*1024);   // private 16x32 bf16
  const int qrow = q0 + w*16 + l15;
  short8_t qf[8];                             // Q fragment, A-layout
#pragma unroll
  for (int kk = 0; kk < 8; ++kk)
    qf[kk] = *(const short8_t*)(Qb + (size_t)qrow*HD + kk*32 + l4*8);
  float4_t oacc[16] = {};
  float m_run[4] = {-1e30f, -1e30f, -1e30f, -1e30f};
  float l_run[4] = {0.f, 0.f, 0.f, 0.f};
  const int nIter = 2*qt + 2;
  for (int kbI = 0; kbI < nIter; ++kbI) {
    const int k0 = kbI * 32;
    __syncthreads();                          // prev iter's LDS reads done
#pragma unroll
    for (int i = 0; i < 4; ++i) {             // K tile: 32 rows x 256, swizzled source col
      int c = tid + i*256;
      int row = c >> 5;
      gload_lds16(Kb + (size_t)(k0 + row)*HD + ((c & 31) ^ (row & 7))*8, (char*)Ks + c*16);
    }
#pragma unroll
    for (int i = 0; i < 4; ++i) {             // V^T tile: 256 rows x 32
      int c = tid + i*256;
      int row = c >> 2;
      gload_lds16(Vb + (size_t)row*S_LEN + k0 + ((c & 3) ^ ((row >> 1) & 3))*8, (char*)VTs + c*16);
    }
    __syncthreads();                          // staging drained
    float4_t sacc[2] = {};
#pragma unroll
    for (int nt = 0; nt < 2; ++nt)
#pragma unroll
      for (int kk = 0; kk < 8; ++kk) {
        short8_t bfr = *(const short8_t*)&Ks[(nt*16 + l15)*HD + ((kk*4 + l4) ^ (l15 & 7))*8];
        sacc[nt] = __builtin_amdgcn_mfma_f32_16x16x32_bf16(qf[kk], bfr, sacc[nt], 0, 0, 0);
      }
    if (kbI >= 2*qt) {                        // causal mask only on the last two k-tiles
#pragma unroll
      for (int nt = 0; nt < 2; ++nt)
#pragma unroll
        for (int r = 0; r < 4; ++r)
          if (k0 + nt*16 + l15 > q0 + w*16 + l4*4 + r) sacc[nt][r] = -1e30f;
    }
    float alpha[4], p[2][4];
#pragma unroll
    for (int r = 0; r < 4; ++r) {
      float m0 = fmaxf(sacc[0][r], sacc[1][r]);
      m0 = fmaxf(m0, DPPF(m0, 0xB1));         // quad_perm xor1
      m0 = fmaxf(m0, DPPF(m0, 0x4E));         // quad_perm xor2
      m0 = fmaxf(m0, DPPF(m0, 0x141));        // row_half_mirror
      m0 = fmaxf(m0, DPPF(m0, 0x140));        // row_mirror -> 16-lane max
      float mnew = fmaxf(m_run[r], m0);
      alpha[r] = exp2f(m_run[r] - mnew);
      m_run[r] = mnew;
      float sum = 0.f;
#pragma unroll
      for (int nt = 0; nt < 2; ++nt) {
        p[nt][r] = exp2f(sacc[nt][r] - mnew);
        sum += p[nt][r];
      }
      sum += DPPF(sum, 0xB1);
      sum += DPPF(sum, 0x4E);
      sum += DPPF(sum, 0x141);
      sum += DPPF(sum, 0x140);                // 16-lane sum
      l_run[r] = l_run[r]*alpha[r] + sum;
    }
#pragma unroll
    for (int nt2 = 0; nt2 < 16; ++nt2) {
      oacc[nt2][0] *= alpha[0];
      oacc[nt2][1] *= alpha[1];
      oacc[nt2][2] *= alpha[2];
      oacc[nt2][3] *= alpha[3];
    }
    // P: D-layout -> A-layout via private LDS (same-wave RAW, lgkmcnt suffices)
#pragma unroll
    for (int nt = 0; nt < 2; ++nt)
#pragma unroll
      for (int r = 0; r < 4; ++r) {
        int prow = l4*4 + r;
        int pcol = nt*16 + l15;
        Pw[prow*32 + (((pcol >> 3) ^ ((prow >> 1) & 3)))*8 + (pcol & 7)] = f2b(p[nt][r]);
      }
    short8_t pf = *(const short8_t*)&Pw[l15*32 + ((l4 ^ ((l15 >> 1) & 3)))*8];
#pragma unroll
    for (int nt2 = 0; nt2 < 16; ++nt2) {
      int vrow = nt2*16 + l15;
      short8_t v0 = *(const short8_t*)&VTs[vrow*32 + ((l4 ^ ((vrow >> 1) & 3)))*8];
      oacc[nt2] = __builtin_amdgcn_mfma_f32_16x16x32_bf16(pf, v0, oacc[nt2], 0, 0, 0);
    }
  }
  float inv_l[4];
#pragma unroll
  for (int r = 0; r < 4; ++r) inv_l[r] = 1.f / l_run[r];
  const int srow0 = q0 + w*16 + l4*4;
#pragma unroll
  for (int nt2 = 0; nt2 < 16; ++nt2) {
    int dim = nt2*16 + l15;
#pragma unroll
    for (int r = 0; r < 4; ++r) {
      int srow = srow0 + r;
      float gv = C1[(size_t)srow*NALL + h*512 + 256 + dim];  // gate pre-activation
      float sg = 1.f / (1.f + __expf(-gv));
      attnb[(size_t)srow*(NH*HD) + h*HD + dim] = f2b(oacc[nt2][r] * inv_l[r] * sg);
    }
  }
}

extern "C" void kernel_launch(void* const* d_in, const int* in_sizes, int n_in,
                              void* d_out, int out_size, void* d_ws, size_t ws_size,
                              hipStream_t stream) {
  const float* hidden = (const float*)d_in[0];
  const float* cosb   = (const float*)d_in[1];
  const float* sinb   = (const float*)d_in[2];
  const float* qw     = (const float*)d_in[3];
  const float* kw     = (const float*)d_in[4];
  const float* vw     = (const float*)d_in[5];
  const float* ow     = (const float*)d_in[6];
  const float* qnw    = (const float*)d_in[7];
  const float* knw    = (const float*)d_in[8];
  float* out    = (float*)d_out;
  float* kcache = out + (size_t)S_LEN*HID;
  float* vcache = kcache + (size_t)NKV*MAXSEQ*HD;

  char* ws = (char*)d_ws;
  size_t off = 0;
  auto alloc = [&](size_t bytes) -> char* {
    char* p = ws + off; off += (bytes + 255) & ~(size_t)255; return p;
  };
  unsigned short* hidb  = (unsigned short*)alloc((size_t)S_LEN*HID*2);     //  8 MB
  unsigned short* wallb = (unsigned short*)alloc((size_t)NALL*HID*2);      // 36 MB
  unsigned short* wob   = (unsigned short*)alloc((size_t)HID*NH*HD*2);     // 16 MB
  float*          C1    = (float*)alloc((size_t)S_LEN*NALL*4);             // 72 MB
  unsigned short* qb    = (unsigned short*)alloc((size_t)NH*S_LEN*HD*2);   // 16 MB
  unsigned short* kb    = (unsigned short*)alloc((size_t)NKV*S_LEN*HD*2);  //  2 MB
  unsigned short* vtb   = (unsigned short*)alloc((size_t)NKV*HD*S_LEN*2);  //  2 MB
  unsigned short* attnb = (unsigned short*)alloc((size_t)S_LEN*NH*HD*2);   // 16 MB

  // all fp32->bf16 converts + cache-pad zeroing in one dispatch
  fused_cvt<<<32768, 256, 0, stream>>>(hidden, qw, kw, vw, ow,
                                       hidb, wallb, wob, kcache, vcache);

  // fused QKV projection: C1 = hidden @ [Wq|Wk|Wv]^T  (2048 x 9216)
  gemm_bt<128,128,4,4><<<dim3(NALL/128, S_LEN/128), 256, 0, stream>>>(
      hidb, wallb, C1, S_LEN, NALL, HID);

  // RMSNorm + RoPE + caches + V^T + q pre-scale
  postproc<<<dim3(S_LEN/4, 20), 256, 0, stream>>>(
      C1, cosb, sinb, qnw, knw, qb, kb, vtb, kcache, vcache);

  // flash attention + sigmoid gate -> attnb (S x H*HD bf16)
  attn_kernel<<<512, 256, 0, stream>>>(qb, kb, vtb, C1, attnb);

  // hidden_out = attnb @ Wo^T  (2048 x 2048, K=4096)
  gemm_bt<128,128,4,4><<<dim3(HID/128, S_LEN/128), 256, 0, stream>>>(
      attnb, wob, out, S_LEN, HID, NH*HD);
}